// Round 1
// 1310.579 us; speedup vs baseline: 1.1186x; 1.1186x over previous
//
#include <hip/hip_runtime.h>
#include <stdint.h>

#define DIMK 4096
#define HD 128
#define NH 32
#define SEQL 2048
#define BSZN 2
#define NROWS (BSZN*SEQL)   // 4096

typedef __bf16 bf16x8 __attribute__((ext_vector_type(8)));
typedef float f32x4 __attribute__((ext_vector_type(4)));
typedef unsigned short u16;
typedef unsigned int u32;

__device__ __forceinline__ float bf2f(u16 h){
  u32 u = ((u32)h) << 16; float f;
  __builtin_memcpy(&f, &u, 4); return f;
}
// round-to-nearest-even f32 -> bf16
__device__ __forceinline__ u16 f2bf(float f){
  u32 u; __builtin_memcpy(&u, &f, 4);
  return (u16)((u + 0x7fffu + ((u >> 16) & 1u)) >> 16);
}

// async global->LDS, 16B/lane; LDS dest is WAVE-UNIFORM base + lane*16B
__device__ __forceinline__ void gld_lds16(const void* g, void* l){
  __builtin_amdgcn_global_load_lds(
      (__attribute__((address_space(1))) void*)(uintptr_t)g,
      (__attribute__((address_space(3))) void*)(uintptr_t)l, 16, 0, 0);
}

// ---------------------------------------------------------------------------
// GEMM (m97 recipe, unchanged this round):
// C[m,n] = sum_k A[m,k]*B[n,k], A/B bf16 row-major 4096x4096.
// 128x128 tile, BK=32, 4 waves (2x2), 16x16x32 bf16 MFMA, 4x4 acc/wave.
// ---------------------------------------------------------------------------
template<int OUTF32>
__device__ __forceinline__ void gemm_core(const u16* __restrict__ A,
                                          const u16* __restrict__ B,
                                          void* __restrict__ Cv,
                                          short* As, short* Bs)
{
  const int tid  = threadIdx.x;
  const int wave = tid >> 6, lane = tid & 63;
  const int wm = wave >> 1, wn = wave & 1;
  const int g = lane >> 4, c16 = lane & 15;
  const int m0 = blockIdx.x * 128, n0 = blockIdx.y * 128;

  const u16* ga[2]; const u16* gb[2]; short* la[2]; short* lb[2];
  #pragma unroll
  for (int p = 0; p < 2; ++p){
    int c = wave*2 + p;
    int row = c*16 + (lane >> 2);
    int col = (lane & 3) * 8;
    ga[p] = A + (size_t)(m0 + row)*DIMK + col;
    gb[p] = B + (size_t)(n0 + row)*DIMK + col;
    la[p] = As + c*512;
    lb[p] = Bs + c*512;
  }

  f32x4 acc[4][4];
  #pragma unroll
  for (int i = 0; i < 4; ++i)
    #pragma unroll
    for (int j = 0; j < 4; ++j)
      acc[i][j] = (f32x4){0.f, 0.f, 0.f, 0.f};

  for (int k0 = 0; k0 < DIMK; k0 += 32){
    #pragma unroll
    for (int p = 0; p < 2; ++p){
      gld_lds16(ga[p], la[p]);
      gld_lds16(gb[p], lb[p]);
      ga[p] += 32; gb[p] += 32;
    }
    __syncthreads();
    bf16x8 af[4], bfr[4];
    #pragma unroll
    for (int i = 0; i < 4; ++i)
      af[i] = *(const bf16x8*)(As + (wm*64 + i*16 + c16)*32 + g*8);
    #pragma unroll
    for (int j = 0; j < 4; ++j)
      bfr[j] = *(const bf16x8*)(Bs + (wn*64 + j*16 + c16)*32 + g*8);
    #pragma unroll
    for (int i = 0; i < 4; ++i)
      #pragma unroll
      for (int j = 0; j < 4; ++j)
        acc[i][j] = __builtin_amdgcn_mfma_f32_16x16x32_bf16(af[i], bfr[j], acc[i][j], 0, 0, 0);
    __syncthreads();
  }

  // C/D layout (m89/m91 verified): col = lane&15, row = (lane>>4)*4 + reg
  if constexpr (OUTF32 == 0){
    u16* C = (u16*)Cv;
    #pragma unroll
    for (int i = 0; i < 4; ++i){
      int mrow = m0 + wm*64 + i*16 + g*4;
      #pragma unroll
      for (int j = 0; j < 4; ++j){
        int ncol = n0 + wn*64 + j*16 + c16;
        #pragma unroll
        for (int r = 0; r < 4; ++r)
          C[(size_t)(mrow + r)*DIMK + ncol] = f2bf(acc[i][j][r]);
      }
    }
  } else {
    float* C = (float*)Cv;
    #pragma unroll
    for (int i = 0; i < 4; ++i){
      int mrow = m0 + wm*64 + i*16 + g*4;
      #pragma unroll
      for (int j = 0; j < 4; ++j){
        int ncol = n0 + wn*64 + j*16 + c16;
        #pragma unroll
        for (int r = 0; r < 4; ++r)
          C[(size_t)(mrow + r)*DIMK + ncol] = acc[i][j][r];
      }
    }
  }
}

__global__ __launch_bounds__(256) void gemm_bf16_kernel(const u16* __restrict__ A,
    const u16* __restrict__ B, u16* __restrict__ C)
{
  __shared__ short As[128*32];
  __shared__ short Bs[128*32];
  gemm_core<0>(A, B, C, As, Bs);
}

__global__ __launch_bounds__(256) void gemm_f32_kernel(const u16* __restrict__ A,
    const u16* __restrict__ B, float* __restrict__ C)
{
  __shared__ short As[128*32];
  __shared__ short Bs[128*32];
  gemm_core<1>(A, B, C, As, Bs);
}

// f32 -> bf16 bulk convert (RNE), 8 elems/thread
__global__ __launch_bounds__(256) void cvt_kernel(const float* __restrict__ src,
                                                  u16* __restrict__ dst, int n8)
{
  int t = blockIdx.x*256 + threadIdx.x;
  if (t >= n8) return;
  const f32x4* s = (const f32x4*)src + (size_t)t*2;
  f32x4 a = s[0], b = s[1];
  ushort4 lo, hi;
  lo.x = f2bf(a[0]); lo.y = f2bf(a[1]); lo.z = f2bf(a[2]); lo.w = f2bf(a[3]);
  hi.x = f2bf(b[0]); hi.y = f2bf(b[1]); hi.z = f2bf(b[2]); hi.w = f2bf(b[3]);
  ushort4* d = (ushort4*)dst + (size_t)t*2;
  d[0] = lo; d[1] = hi;
}

// ---------------------------------------------------------------------------
// V (B,S,DIM row-major) -> V^T ([b][h][d][s]); 64x64 LDS tile per block
// ---------------------------------------------------------------------------
__global__ __launch_bounds__(256) void transpose_kernel(const u16* __restrict__ v,
                                                        u16* __restrict__ vt)
{
  __shared__ u16 tile[64][72];
  const int t  = threadIdx.x;
  const int s0 = blockIdx.x * 64;
  const int d0 = blockIdx.y * 64;
  const int bh = blockIdx.z;
  const int b = bh >> 5, h = bh & 31;

  #pragma unroll
  for (int i = 0; i < 4; ++i){
    int row = i*16 + (t >> 4);
    int cc  = (t & 15) * 4;
    uint2 val = *(const uint2*)(v + (size_t)(b*SEQL + s0 + row)*DIMK + h*HD + d0 + cc);
    const u16* p4 = (const u16*)&val;
    #pragma unroll
    for (int j = 0; j < 4; ++j) tile[cc + j][row] = p4[j];
  }
  __syncthreads();
  #pragma unroll
  for (int i = 0; i < 4; ++i){
    int drow = i*16 + (t >> 4);
    int sc   = (t & 15) * 4;
    uint2 o; u16* po = (u16*)&o;
    #pragma unroll
    for (int j = 0; j < 4; ++j) po[j] = tile[drow][sc + j];
    *(uint2*)(vt + ((size_t)(b*NH + h)*HD + d0 + drow)*SEQL + s0 + sc) = o;
  }
}

// ---------------------------------------------------------------------------
// RoPE (interleaved pairs), OUT-OF-PLACE: qsrc->qdst, ksrc->kdst; freqs f32
// ---------------------------------------------------------------------------
__global__ __launch_bounds__(256) void rope_kernel(const u16* __restrict__ qsrc,
    const u16* __restrict__ ksrc, u16* __restrict__ qdst, u16* __restrict__ kdst,
    const float* __restrict__ fc, const float* __restrict__ fs)
{
  const size_t PER = (size_t)NROWS * DIMK / 8;
  size_t t = (size_t)blockIdx.x * 256 + threadIdx.x;
  const u16* src = qsrc; u16* dst = qdst;
  if (t >= PER){ src = ksrc; dst = kdst; t -= PER; }
  size_t e0 = t * 8;
  int row = (int)(e0 >> 12);
  int col = (int)(e0 & (DIMK-1));
  int s  = row & (SEQL-1);
  int i0 = (col & (HD-1)) >> 1;

  uint4 raw = *(const uint4*)(src + e0);
  u16* xs = (u16*)&raw;
  f32x4 c4 = *(const f32x4*)(fc + s*64 + i0);
  f32x4 s4 = *(const f32x4*)(fs + s*64 + i0);
  #pragma unroll
  for (int j = 0; j < 4; ++j){
    float e = bf2f(xs[2*j]), o = bf2f(xs[2*j+1]);
    float c = c4[j], sn = s4[j];
    xs[2*j]   = f2bf(e*c - o*sn);
    xs[2*j+1] = f2bf(e*sn + o*c);
  }
  *(uint4*)(dst + e0) = raw;
}

// ---------------------------------------------------------------------------
// Flash attention, causal. 4 waves = 128 Q rows/block. Bc=64 K-cols/step.
// Round 5 rewrite:
//  - K/V staged via global_load_lds (16B) into LINEAR LDS with m214 XOR
//    swizzle (byte ^= (row&7)<<4), applied by pre-swizzling the per-lane
//    GLOBAL source address (rule #21: both-sides-or-neither).
//  - K single-buffered, V double-buffered. 2 barriers/step:
//      A (top): staged tile visible (compiler's vmcnt(0) drain does the wait)
//      B (post-QK^T): K reads complete block-wide -> restage Ks safely.
//    Next-tile stages are ISSUED right after B, so the global loads fly
//    under softmax + P-write + PV and drain only at the next A.
//  - P strip is PER-WAVE: full __syncthreads replaced by
//    s_waitcnt lgkmcnt(0) + sched_barrier(0) (rule #18 pattern).
//  - grid (bh=64, qtiles=16), qt = 15 - y: all heavy diagonal blocks
//    dispatch first (tail balance); 64%8==0 pins each bh to one XCD.
// ---------------------------------------------------------------------------
__device__ __forceinline__ void stage_k_tile(const u16* kb, int s0, short* Ksd,
                                             int wave, int g, int c16){
  #pragma unroll
  for (int it = 0; it < 4; ++it){
    int rbase = it*16 + wave*4;       // wave-uniform
    int row = rbase + g;              // per-lane
    gld_lds16(kb + (size_t)(s0 + row)*DIMK + ((c16 ^ (row & 7)) << 3),
              Ksd + rbase*128);
  }
}
__device__ __forceinline__ void stage_v_tile(const u16* vb, int s0, short* Vd,
                                             int wave, int lane){
  const int sc = lane & 7, rg = lane >> 3;
  #pragma unroll
  for (int it = 0; it < 4; ++it){
    int rbase = (it*4 + wave)*8;      // wave-uniform
    int row = rbase + rg;             // per-lane
    gld_lds16(vb + (size_t)row*SEQL + s0 + ((sc ^ (row & 7)) << 3),
              Vd + rbase*64);
  }
}

__global__ __launch_bounds__(256) void flash_kernel(const u16* __restrict__ Q,
    const u16* __restrict__ K, const u16* __restrict__ Vt, u16* __restrict__ AO)
{
  __shared__ short Ks[64*128];       // [s][d] swizzled, single buffer (16 KB)
  __shared__ short Vs[2*128*64];     // [d][s] swizzled, double buffer (32 KB)
  __shared__ short Ps[4*32*64];      // per-wave P strips, swizzled (16 KB)

  const int bh = blockIdx.x;
  const int qt = 15 - (int)blockIdx.y;         // heavy diagonal first
  const int b = bh >> 5, h = bh & 31;
  const int tid = threadIdx.x;
  const int wave = tid >> 6, lane = tid & 63;
  const int g = lane >> 4, c16 = lane & 15;
  const int qr0 = qt*128 + wave*32;

  const u16* kb = K  + (size_t)(b*SEQL)*DIMK + h*HD;
  const u16* vb = Vt + (size_t)(b*NH + h)*HD*SEQL;
  short* Pw = Ps + wave*(32*64);

  // prologue: get tile 0 flying before anything else
  stage_k_tile(kb, 0, Ks, wave, g, c16);
  stage_v_tile(vb, 0, Vs, wave, lane);

  bf16x8 qa[2][4];
  #pragma unroll
  for (int rt = 0; rt < 2; ++rt){
    const u16* qp = Q + (size_t)(b*SEQL + qr0 + rt*16 + c16)*DIMK + h*HD + g*8;
    #pragma unroll
    for (int kc = 0; kc < 4; ++kc)
      qa[rt][kc] = *(const bf16x8*)(qp + kc*32);
  }

  f32x4 oacc[2][8];
  #pragma unroll
  for (int rt = 0; rt < 2; ++rt)
    #pragma unroll
    for (int dt = 0; dt < 8; ++dt)
      oacc[rt][dt] = (f32x4){0.f, 0.f, 0.f, 0.f};
  float m_st[2][4], l_st[2][4];
  #pragma unroll
  for (int rt = 0; rt < 2; ++rt)
    #pragma unroll
    for (int r = 0; r < 4; ++r){ m_st[rt][r] = -1e30f; l_st[rt][r] = 0.f; }

  const int nsteps = 2*(qt + 1);
  for (int kt = 0; kt < nsteps; ++kt){
    const int s0 = kt*64;
    const short* Vsc = Vs + (kt & 1)*(128*64);
    const bool alive = (s0 <= qr0 + 31);       // wave-uniform

    __syncthreads();   // A: implicit vmcnt(0) drain -> staged K/V visible;
                       //    also separates prev-step P/V reads from writes

    f32x4 sacc[2][4];
    if (alive){
      #pragma unroll
      for (int rt = 0; rt < 2; ++rt)
        #pragma unroll
        for (int ct = 0; ct < 4; ++ct)
          sacc[rt][ct] = (f32x4){0.f, 0.f, 0.f, 0.f};
      // S = Q K^T (swizzled K reads)
      __builtin_amdgcn_s_setprio(1);
      #pragma unroll
      for (int kc = 0; kc < 4; ++kc){
        #pragma unroll
        for (int ct = 0; ct < 4; ++ct){
          int row = ct*16 + c16;
          bf16x8 bfr = *(const bf16x8*)(Ks + row*128 + (((g + 4*kc) ^ (row & 7)) << 3));
          sacc[0][ct] = __builtin_amdgcn_mfma_f32_16x16x32_bf16(qa[0][kc], bfr, sacc[0][ct], 0, 0, 0);
          sacc[1][ct] = __builtin_amdgcn_mfma_f32_16x16x32_bf16(qa[1][kc], bfr, sacc[1][ct], 0, 0, 0);
        }
      }
      __builtin_amdgcn_s_setprio(0);
    }

    __syncthreads();   // B: all K reads done block-wide (vmcnt already 0 here)

    // issue next-tile stages NOW: they fly under softmax + P + PV,
    // drained only at the next iteration's barrier A
    if (kt + 1 < nsteps){
      stage_k_tile(kb, s0 + 64, Ks, wave, g, c16);
      stage_v_tile(vb, s0 + 64, Vs + ((kt+1) & 1)*(128*64), wave, lane);
    }

    if (alive){
      // scale + causal mask (C layout: row = g*4+r, col = c16)
      const float scale = 0.08838834764831845f;
      #pragma unroll
      for (int rt = 0; rt < 2; ++rt){
        int rowb = qr0 + rt*16 + g*4;
        #pragma unroll
        for (int ct = 0; ct < 4; ++ct){
          int scol = s0 + ct*16 + c16;
          #pragma unroll
          for (int r = 0; r < 4; ++r){
            float v = sacc[rt][ct][r] * scale;
            sacc[rt][ct][r] = (scol <= rowb + r) ? v : -1e30f;
          }
        }
      }

      // online softmax update (row state replicated across 16-lane group)
      #pragma unroll
      for (int rt = 0; rt < 2; ++rt){
        #pragma unroll
        for (int r = 0; r < 4; ++r){
          float mx = fmaxf(fmaxf(sacc[rt][0][r], sacc[rt][1][r]),
                           fmaxf(sacc[rt][2][r], sacc[rt][3][r]));
          #pragma unroll
          for (int off = 1; off < 16; off <<= 1)
            mx = fmaxf(mx, __shfl_xor(mx, off));
          float mn = fmaxf(m_st[rt][r], mx);
          float al = __expf(m_st[rt][r] - mn);
          m_st[rt][r] = mn;
          float sum = 0.f;
          #pragma unroll
          for (int ct = 0; ct < 4; ++ct){
            float pv = __expf(sacc[rt][ct][r] - mn);
            sacc[rt][ct][r] = pv;
            sum += pv;
          }
          #pragma unroll
          for (int off = 1; off < 16; off <<= 1)
            sum += __shfl_xor(sum, off);
          l_st[rt][r] = l_st[rt][r]*al + sum;
          #pragma unroll
          for (int dt = 0; dt < 8; ++dt)
            oacc[rt][dt][r] *= al;
        }
      }

      // P -> per-wave LDS strip (swizzled scatter)
      #pragma unroll
      for (int rt = 0; rt < 2; ++rt)
        #pragma unroll
        for (int ct = 0; ct < 4; ++ct)
          #pragma unroll
          for (int r = 0; r < 4; ++r){
            int prow = rt*16 + g*4 + r;
            int pcol = ct*16 + c16;
            Pw[prow*64 + ((((pcol >> 3) ^ (prow & 7)) << 3) | (pcol & 7))] =
                (short)f2bf(sacc[rt][ct][r]);
          }

      // per-wave strip: lgkm drain + sched fence instead of __syncthreads
      asm volatile("s_waitcnt lgkmcnt(0)" ::: "memory");
      __builtin_amdgcn_sched_barrier(0);

      // O += P V  (swizzled P and V reads)
      __builtin_amdgcn_s_setprio(1);
      #pragma unroll
      for (int kc2 = 0; kc2 < 2; ++kc2){
        int pr0 = c16, pr1 = 16 + c16;
        bf16x8 pf0 = *(const bf16x8*)(Pw + pr0*64 + (((g + 4*kc2) ^ (pr0 & 7)) << 3));
        bf16x8 pf1 = *(const bf16x8*)(Pw + pr1*64 + (((g + 4*kc2) ^ (pr1 & 7)) << 3));
        #pragma unroll
        for (int dt = 0; dt < 8; ++dt){
          int vr = dt*16 + c16;
          bf16x8 vf = *(const bf16x8*)(Vsc + vr*64 + (((g + 4*kc2) ^ (vr & 7)) << 3));
          oacc[0][dt] = __builtin_amdgcn_mfma_f32_16x16x32_bf16(pf0, vf, oacc[0][dt], 0, 0, 0);
          oacc[1][dt] = __builtin_amdgcn_mfma_f32_16x16x32_bf16(pf1, vf, oacc[1][dt], 0, 0, 0);
        }
      }
      __builtin_amdgcn_s_setprio(0);
    }
  }

  // normalize + store (B,S,DIM)
  #pragma unroll
  for (int rt = 0; rt < 2; ++rt){
    float inv[4];
    #pragma unroll
    for (int r = 0; r < 4; ++r) inv[r] = 1.0f / l_st[rt][r];
    #pragma unroll
    for (int dt = 0; dt < 8; ++dt){
      #pragma unroll
      for (int r = 0; r < 4; ++r){
        int qrow = qr0 + rt*16 + g*4 + r;
        int col  = h*HD + dt*16 + c16;
        AO[(size_t)(b*SEQL + qrow)*DIMK + col] = f2bf(oacc[rt][dt][r] * inv[r]);
      }
    }
  }
}

extern "C" void kernel_launch(void* const* d_in, const int* in_sizes, int n_in,
                              void* d_out, int out_size, void* d_ws, size_t ws_size,
                              hipStream_t stream)
{
  const float* x  = (const float*)d_in[0];
  const float* wq = (const float*)d_in[1];
  const float* wk = (const float*)d_in[2];
  const float* wv = (const float*)d_in[3];
  const float* wo = (const float*)d_in[4];
  const float* fc = (const float*)d_in[5];
  const float* fs = (const float*)d_in[6];
  float* out = (float*)d_out;

  const size_t TEN  = (size_t)NROWS * DIMK;    // 16,777,216 elems
  const size_t TENB = TEN * sizeof(u16);       // 32 MiB
  const int N8 = (int)(TEN / 8);

  const dim3 G(32, 32), B256(256);
  const dim3 FG(64, 16);                        // (bh, qtiles) — heavy-first inside

  if (ws_size >= 8 * TENB){
    u16* xb   = (u16*)d_ws;
    u16* wb   = xb   + TEN;
    u16* qb   = wb   + TEN;
    u16* kb   = qb   + TEN;
    u16* vraw = kb   + TEN;
    u16* vtb  = vraw + TEN;
    u16* qro  = vtb  + TEN;
    u16* kro  = qro  + TEN;
    cvt_kernel<<<dim3(8192), B256, 0, stream>>>(x,  xb, N8);
    cvt_kernel<<<dim3(8192), B256, 0, stream>>>(wq, wb, N8);
    gemm_bf16_kernel<<<G, B256, 0, stream>>>(xb, wb, qb);
    cvt_kernel<<<dim3(8192), B256, 0, stream>>>(wk, wb, N8);
    gemm_bf16_kernel<<<G, B256, 0, stream>>>(xb, wb, kb);
    cvt_kernel<<<dim3(8192), B256, 0, stream>>>(wv, wb, N8);
    gemm_bf16_kernel<<<G, B256, 0, stream>>>(xb, wb, vraw);
    transpose_kernel<<<dim3(32, 2, 64), B256, 0, stream>>>(vraw, vtb);
    rope_kernel<<<dim3(16384), B256, 0, stream>>>(qb, kb, qro, kro, fc, fs);
    flash_kernel<<<FG, B256, 0, stream>>>(qro, kro, vtb, vraw); // AO->vraw
    cvt_kernel<<<dim3(8192), B256, 0, stream>>>(wo, xb, N8);    // xb dead
    gemm_f32_kernel<<<G, B256, 0, stream>>>(vraw, xb, out);
  } else if (ws_size >= 4 * TENB){
    u16* xb  = (u16*)d_out;
    u16* wb  = xb + TEN;
    u16* qb  = (u16*)d_ws;
    u16* kb  = qb + TEN;
    u16* vtb = kb + TEN;
    u16* s3  = vtb + TEN;                       // Vraw, then roped-Q
    cvt_kernel<<<dim3(8192), B256, 0, stream>>>(x,  xb, N8);
    cvt_kernel<<<dim3(8192), B256, 0, stream>>>(wq, wb, N8);
    gemm_bf16_kernel<<<G, B256, 0, stream>>>(xb, wb, qb);
    cvt_kernel<<<dim3(8192), B256, 0, stream>>>(wk, wb, N8);
    gemm_bf16_kernel<<<G, B256, 0, stream>>>(xb, wb, kb);
    cvt_kernel<<<dim3(8192), B256, 0, stream>>>(wv, wb, N8);
    gemm_bf16_kernel<<<G, B256, 0, stream>>>(xb, wb, s3);                 // Vraw
    transpose_kernel<<<dim3(32, 2, 64), B256, 0, stream>>>(s3, vtb);
    rope_kernel<<<dim3(16384), B256, 0, stream>>>(qb, kb, s3, xb, fc, fs); // qro=s3, kro=xb
    flash_kernel<<<FG, B256, 0, stream>>>(s3, xb, vtb, qb);                // AO->qb
    cvt_kernel<<<dim3(8192), B256, 0, stream>>>(wo, kb, N8);               // kb dead
    gemm_f32_kernel<<<G, B256, 0, stream>>>(qb, kb, out);
  }
}

// Round 2
// 1037.423 us; speedup vs baseline: 1.4131x; 1.2633x over previous
//
#include <hip/hip_runtime.h>
#include <stdint.h>

#define DIMK 4096
#define HD 128
#define NH 32
#define SEQL 2048
#define BSZN 2
#define NROWS (BSZN*SEQL)   // 4096

typedef __bf16 bf16x8 __attribute__((ext_vector_type(8)));
typedef float f32x4 __attribute__((ext_vector_type(4)));
typedef unsigned short u16;
typedef unsigned int u32;

__device__ __forceinline__ float bf2f(u16 h){
  u32 u = ((u32)h) << 16; float f;
  __builtin_memcpy(&f, &u, 4); return f;
}
// round-to-nearest-even f32 -> bf16
__device__ __forceinline__ u16 f2bf(float f){
  u32 u; __builtin_memcpy(&u, &f, 4);
  return (u16)((u + 0x7fffu + ((u >> 16) & 1u)) >> 16);
}

// async global->LDS, 16B/lane; LDS dest is WAVE-UNIFORM base + lane*16B
__device__ __forceinline__ void gld_lds16(const void* g, void* l){
  __builtin_amdgcn_global_load_lds(
      (__attribute__((address_space(1))) void*)(uintptr_t)g,
      (__attribute__((address_space(3))) void*)(uintptr_t)l, 16, 0, 0);
}

// ---------------------------------------------------------------------------
// GEMM, 256x256 8-phase schedule (m201/T2+T3+T4+T5 port, plain HIP):
// C[m,n] = sum_k A[m,k]*B[n,k], A/B bf16 row-major 4096x4096.
// - 512 thr = 8 waves (2M x 4N), interleaved 16-blocks: wave (wm,wn) owns
//   row-blocks {2i+wm} and col-blocks {4n+wn}  ->  per phase, A/B LDS halves
//   are read by ALL waves simultaneously (required for the stage schedule).
// - BK=64, 2 K-tiles/iter, 8 phases/iter. LDS 128 KiB = 2 buf x (A 32K + B 32K),
//   each operand as 2 halves of [128 rows][64 cols] bf16, XOR-16B-chunk swizzle
//   (chunk ^= row&7), applied via pre-swizzled GLOBAL source (rule #21).
// - per phase: {ds_reads | 1 half-tile stage (2x gld_lds16)} ; s_barrier ;
//   lgkmcnt(0) ; setprio(1) 16xMFMA setprio(0) ; s_barrier.
// - counted vmcnt(6) ONLY at phases 3 and 7 (3 half-tiles stay in flight).
// Stage slots (iter i): p0: buf1.B0<-t(2i+1) | p1: buf0.A0<-t(2i+2) |
//   p2: buf0.B1 | p3: buf0.A1 +vmcnt6 | p4: buf0.B0 | p5: buf1.A0<-t(2i+3) |
//   p6: buf1.B1 | p7: buf1.A1 +vmcnt6.
// Reads per buf: A0@q0, B1@q1, A1@q2, B0@q0&q3(re-read) -- every slot lands
// >=4 phases before its read and >=1 barrier after the region's last read.
// ---------------------------------------------------------------------------
#define BARX __builtin_amdgcn_s_barrier()
#define LGKM0 asm volatile("s_waitcnt lgkmcnt(0)" ::: "memory")
#define VMC6  asm volatile("s_waitcnt vmcnt(6)"  ::: "memory")
#define SP1 __builtin_amdgcn_s_setprio(1)
#define SP0 __builtin_amdgcn_s_setprio(0)

#define LDA4(MB, Ab) do{ \
  _Pragma("unroll") for (int mi = 0; mi < 4; ++mi){ \
    const int m_ = (MB) + mi; \
    const short* _p = (Ab) + (m_>>2)*8192 + (m_&3)*2048 + rdA; \
    aF[mi][0] = *(const bf16x8*)(_p + ch0); \
    aF[mi][1] = *(const bf16x8*)(_p + ch1); } }while(0)

#define LDB2(NB, Bb) do{ \
  _Pragma("unroll") for (int ni = 0; ni < 2; ++ni){ \
    const int n_ = (NB) + ni; \
    const short* _p = (Bb) + (n_>>1)*8192 + (n_&1)*4096 + rdB; \
    bF[ni][0] = *(const bf16x8*)(_p + ch0); \
    bF[ni][1] = *(const bf16x8*)(_p + ch1); } }while(0)

#define MFMA16(MB, NB) do{ \
  _Pragma("unroll") for (int ks = 0; ks < 2; ++ks) \
  _Pragma("unroll") for (int mi = 0; mi < 4; ++mi) \
  _Pragma("unroll") for (int ni = 0; ni < 2; ++ni) \
    acc[(MB)+mi][(NB)+ni] = __builtin_amdgcn_mfma_f32_16x16x32_bf16( \
        aF[mi][ks], bF[ni][ks], acc[(MB)+mi][(NB)+ni], 0, 0, 0); }while(0)

#define STG_A(buf,h,kt) do{ \
    size_t _o = ((size_t)(h)<<19) + (size_t)(kt)*64; \
    short* _d = dA + (buf)*32768 + (h)*8192; \
    gld_lds16(sA[0]+_o, _d); gld_lds16(sA[1]+_o, _d+512); }while(0)

#define STG_B(buf,h,kt) do{ \
    size_t _o = ((size_t)(h)<<19) + (size_t)(kt)*64; \
    short* _d = dB + (buf)*32768 + (h)*8192; \
    gld_lds16(sB[0]+_o, _d); gld_lds16(sB[1]+_o, _d+512); }while(0)

template<int OUTF32>
__device__ __forceinline__ void gemm256_core(const u16* __restrict__ A,
                                             const u16* __restrict__ B,
                                             void* __restrict__ Cv,
                                             short* SMEM)
{
  const int tid  = threadIdx.x;
  const int wave = tid >> 6, lane = tid & 63;
  const int wm = wave >> 2, wn = wave & 3;
  const int g = lane >> 4, c16 = lane & 15;

  // XCD-chunked swizzle: 256 blocks, 8 XCDs, each XCD owns a 4x8 (bx,by) tile
  const int bid = blockIdx.x;
  const int xcd = bid & 7, cc = bid >> 3;
  const int bx = (xcd & 3)*4 + (cc & 3);
  const int by = (xcd >> 2)*8 + (cc >> 2);
  const int m0 = bx*256, n0 = by*256;

  // LDS read constants (shorts). chunk' = (ks*4+g) ^ (c16&7); ch1 = ch0 ^ 4chunks
  const int ch0 = ((g ^ (c16 & 7)) << 3);
  const int ch1 = ch0 ^ 32;
  const int rdA = wm*1024 + c16*64;
  const int rdB = wn*1024 + c16*64;

  // stage sources: wave w, load p covers rows j*8..j*8+7 (j=w*2+p) of the half;
  // global col pre-swizzled so linear LDS + swizzled read line up (rule #21)
  const int swzc = (((lane & 7) ^ ((lane >> 3) & 7)) << 3);
  const u16* sA[2]; const u16* sB[2];
  #pragma unroll
  for (int p = 0; p < 2; ++p){
    int rr = wave*16 + p*8 + (lane >> 3);
    sA[p] = A + (size_t)(m0 + rr)*DIMK + swzc;
    sB[p] = B + (size_t)(n0 + rr)*DIMK + swzc;
  }
  short* const dA = SMEM + wave*1024;
  short* const dB = SMEM + 16384 + wave*1024;

  const short* A0 = SMEM;
  const short* B0 = SMEM + 16384;
  const short* A1 = SMEM + 32768;
  const short* B1 = SMEM + 49152;

  f32x4 acc[8][4];
  #pragma unroll
  for (int m = 0; m < 8; ++m)
    #pragma unroll
    for (int n = 0; n < 4; ++n)
      acc[m][n] = (f32x4){0.f, 0.f, 0.f, 0.f};

  bf16x8 aF[4][2], bF[2][2];

  // prologue: buf0 <- tile 0 (all 4 halves), buf1 <- tile 1 (A0,B1,A1).
  // vmcnt(6) retires the 8 oldest loads = all of buf0.
  STG_A(0,0,0); STG_B(0,1,0); STG_A(0,1,0); STG_B(0,0,0);
  STG_A(1,0,1); STG_B(1,1,1); STG_A(1,1,1);
  VMC6; BARX;

  #pragma unroll 1
  for (int i = 0; i < 32; ++i){
    const int t1 = (2*i+1) & 63, t2 = (2*i+2) & 63, t3 = (2*i+3) & 63;
    // ---- p0: tile 2i, Q(m-lo, n-lo)
    LDA4(0, A0); LDB2(0, B0);
    STG_B(1, 0, t1);
    BARX; LGKM0;
    SP1; MFMA16(0, 0); SP0;
    BARX;
    // ---- p1: Q(m-lo, n-hi)
    LDB2(2, B0);
    STG_A(0, 0, t2);
    BARX; LGKM0;
    SP1; MFMA16(0, 2); SP0;
    BARX;
    // ---- p2: Q(m-hi, n-hi)
    LDA4(4, A0);
    STG_B(0, 1, t2);
    BARX; LGKM0;
    SP1; MFMA16(4, 2); SP0;
    BARX;
    // ---- p3: Q(m-hi, n-lo)  (B-lo re-read)
    LDB2(0, B0);
    STG_A(0, 1, t2);
    VMC6;
    BARX; LGKM0;
    SP1; MFMA16(4, 0); SP0;
    BARX;
    // ---- p4: tile 2i+1, Q(m-lo, n-lo)
    LDA4(0, A1); LDB2(0, B1);
    STG_B(0, 0, t2);
    BARX; LGKM0;
    SP1; MFMA16(0, 0); SP0;
    BARX;
    // ---- p5: Q(m-lo, n-hi)
    LDB2(2, B1);
    STG_A(1, 0, t3);
    BARX; LGKM0;
    SP1; MFMA16(0, 2); SP0;
    BARX;
    // ---- p6: Q(m-hi, n-hi)
    LDA4(4, A1);
    STG_B(1, 1, t3);
    BARX; LGKM0;
    SP1; MFMA16(4, 2); SP0;
    BARX;
    // ---- p7: Q(m-hi, n-lo)
    LDB2(0, B1);
    STG_A(1, 1, t3);
    VMC6;
    BARX; LGKM0;
    SP1; MFMA16(4, 0); SP0;
    BARX;
  }

  // epilogue: frag (m,n) -> rows m0+(2m+wm)*16+g*4+r, col n0+(4n+wn)*16+c16
  if constexpr (OUTF32 == 0){
    u16* C = (u16*)Cv;
    #pragma unroll
    for (int m = 0; m < 8; ++m){
      int row0 = m0 + (m*2 + wm)*16 + g*4;
      #pragma unroll
      for (int n = 0; n < 4; ++n){
        int col = n0 + (n*4 + wn)*16 + c16;
        #pragma unroll
        for (int r = 0; r < 4; ++r)
          C[(size_t)(row0 + r)*DIMK + col] = f2bf(acc[m][n][r]);
      }
    }
  } else {
    float* C = (float*)Cv;
    #pragma unroll
    for (int m = 0; m < 8; ++m){
      int row0 = m0 + (m*2 + wm)*16 + g*4;
      #pragma unroll
      for (int n = 0; n < 4; ++n){
        int col = n0 + (n*4 + wn)*16 + c16;
        #pragma unroll
        for (int r = 0; r < 4; ++r)
          C[(size_t)(row0 + r)*DIMK + col] = acc[m][n][r];
      }
    }
  }
}

__global__ __launch_bounds__(512, 2) void gemm_bf16_kernel(const u16* __restrict__ A,
    const u16* __restrict__ B, u16* __restrict__ C)
{
  __shared__ __align__(16) short SMEM[65536];   // 128 KiB
  gemm256_core<0>(A, B, C, SMEM);
}

__global__ __launch_bounds__(512, 2) void gemm_f32_kernel(const u16* __restrict__ A,
    const u16* __restrict__ B, float* __restrict__ C)
{
  __shared__ __align__(16) short SMEM[65536];
  gemm256_core<1>(A, B, C, SMEM);
}

// f32 -> bf16 bulk convert (RNE), 8 elems/thread
__global__ __launch_bounds__(256) void cvt_kernel(const float* __restrict__ src,
                                                  u16* __restrict__ dst, int n8)
{
  int t = blockIdx.x*256 + threadIdx.x;
  if (t >= n8) return;
  const f32x4* s = (const f32x4*)src + (size_t)t*2;
  f32x4 a = s[0], b = s[1];
  ushort4 lo, hi;
  lo.x = f2bf(a[0]); lo.y = f2bf(a[1]); lo.z = f2bf(a[2]); lo.w = f2bf(a[3]);
  hi.x = f2bf(b[0]); hi.y = f2bf(b[1]); hi.z = f2bf(b[2]); hi.w = f2bf(b[3]);
  ushort4* d = (ushort4*)dst + (size_t)t*2;
  d[0] = lo; d[1] = hi;
}

// ---------------------------------------------------------------------------
// V (B,S,DIM row-major) -> V^T ([b][h][d][s]); 64x64 LDS tile per block
// ---------------------------------------------------------------------------
__global__ __launch_bounds__(256) void transpose_kernel(const u16* __restrict__ v,
                                                        u16* __restrict__ vt)
{
  __shared__ u16 tile[64][72];
  const int t  = threadIdx.x;
  const int s0 = blockIdx.x * 64;
  const int d0 = blockIdx.y * 64;
  const int bh = blockIdx.z;
  const int b = bh >> 5, h = bh & 31;

  #pragma unroll
  for (int i = 0; i < 4; ++i){
    int row = i*16 + (t >> 4);
    int cc  = (t & 15) * 4;
    uint2 val = *(const uint2*)(v + (size_t)(b*SEQL + s0 + row)*DIMK + h*HD + d0 + cc);
    const u16* p4 = (const u16*)&val;
    #pragma unroll
    for (int j = 0; j < 4; ++j) tile[cc + j][row] = p4[j];
  }
  __syncthreads();
  #pragma unroll
  for (int i = 0; i < 4; ++i){
    int drow = i*16 + (t >> 4);
    int sc   = (t & 15) * 4;
    uint2 o; u16* po = (u16*)&o;
    #pragma unroll
    for (int j = 0; j < 4; ++j) po[j] = tile[drow][sc + j];
    *(uint2*)(vt + ((size_t)(b*NH + h)*HD + d0 + drow)*SEQL + s0 + sc) = o;
  }
}

// ---------------------------------------------------------------------------
// RoPE (interleaved pairs), OUT-OF-PLACE: qsrc->qdst, ksrc->kdst; freqs f32
// ---------------------------------------------------------------------------
__global__ __launch_bounds__(256) void rope_kernel(const u16* __restrict__ qsrc,
    const u16* __restrict__ ksrc, u16* __restrict__ qdst, u16* __restrict__ kdst,
    const float* __restrict__ fc, const float* __restrict__ fs)
{
  const size_t PER = (size_t)NROWS * DIMK / 8;
  size_t t = (size_t)blockIdx.x * 256 + threadIdx.x;
  const u16* src = qsrc; u16* dst = qdst;
  if (t >= PER){ src = ksrc; dst = kdst; t -= PER; }
  size_t e0 = t * 8;
  int row = (int)(e0 >> 12);
  int col = (int)(e0 & (DIMK-1));
  int s  = row & (SEQL-1);
  int i0 = (col & (HD-1)) >> 1;

  uint4 raw = *(const uint4*)(src + e0);
  u16* xs = (u16*)&raw;
  f32x4 c4 = *(const f32x4*)(fc + s*64 + i0);
  f32x4 s4 = *(const f32x4*)(fs + s*64 + i0);
  #pragma unroll
  for (int j = 0; j < 4; ++j){
    float e = bf2f(xs[2*j]), o = bf2f(xs[2*j+1]);
    float c = c4[j], sn = s4[j];
    xs[2*j]   = f2bf(e*c - o*sn);
    xs[2*j+1] = f2bf(e*sn + o*c);
  }
  *(uint4*)(dst + e0) = raw;
}

// ---------------------------------------------------------------------------
// Flash attention, causal (round-1 version, verified). 4 waves = 128 Q rows.
// ---------------------------------------------------------------------------
__device__ __forceinline__ void stage_k_tile(const u16* kb, int s0, short* Ksd,
                                             int wave, int g, int c16){
  #pragma unroll
  for (int it = 0; it < 4; ++it){
    int rbase = it*16 + wave*4;       // wave-uniform
    int row = rbase + g;              // per-lane
    gld_lds16(kb + (size_t)(s0 + row)*DIMK + ((c16 ^ (row & 7)) << 3),
              Ksd + rbase*128);
  }
}
__device__ __forceinline__ void stage_v_tile(const u16* vb, int s0, short* Vd,
                                             int wave, int lane){
  const int sc = lane & 7, rg = lane >> 3;
  #pragma unroll
  for (int it = 0; it < 4; ++it){
    int rbase = (it*4 + wave)*8;      // wave-uniform
    int row = rbase + rg;             // per-lane
    gld_lds16(vb + (size_t)row*SEQL + s0 + ((sc ^ (row & 7)) << 3),
              Vd + rbase*64);
  }
}

__global__ __launch_bounds__(256) void flash_kernel(const u16* __restrict__ Q,
    const u16* __restrict__ K, const u16* __restrict__ Vt, u16* __restrict__ AO)
{
  __shared__ short Ks[64*128];       // [s][d] swizzled, single buffer (16 KB)
  __shared__ short Vs[2*128*64];     // [d][s] swizzled, double buffer (32 KB)
  __shared__ short Ps[4*32*64];      // per-wave P strips, swizzled (16 KB)

  const int bh = blockIdx.x;
  const int qt = 15 - (int)blockIdx.y;         // heavy diagonal first
  const int b = bh >> 5, h = bh & 31;
  const int tid = threadIdx.x;
  const int wave = tid >> 6, lane = tid & 63;
  const int g = lane >> 4, c16 = lane & 15;
  const int qr0 = qt*128 + wave*32;

  const u16* kb = K  + (size_t)(b*SEQL)*DIMK + h*HD;
  const u16* vb = Vt + (size_t)(b*NH + h)*HD*SEQL;
  short* Pw = Ps + wave*(32*64);

  // prologue: get tile 0 flying before anything else
  stage_k_tile(kb, 0, Ks, wave, g, c16);
  stage_v_tile(vb, 0, Vs, wave, lane);

  bf16x8 qa[2][4];
  #pragma unroll
  for (int rt = 0; rt < 2; ++rt){
    const u16* qp = Q + (size_t)(b*SEQL + qr0 + rt*16 + c16)*DIMK + h*HD + g*8;
    #pragma unroll
    for (int kc = 0; kc < 4; ++kc)
      qa[rt][kc] = *(const bf16x8*)(qp + kc*32);
  }

  f32x4 oacc[2][8];
  #pragma unroll
  for (int rt = 0; rt < 2; ++rt)
    #pragma unroll
    for (int dt = 0; dt < 8; ++dt)
      oacc[rt][dt] = (f32x4){0.f, 0.f, 0.f, 0.f};
  float m_st[2][4], l_st[2][4];
  #pragma unroll
  for (int rt = 0; rt < 2; ++rt)
    #pragma unroll
    for (int r = 0; r < 4; ++r){ m_st[rt][r] = -1e30f; l_st[rt][r] = 0.f; }

  const int nsteps = 2*(qt + 1);
  for (int kt = 0; kt < nsteps; ++kt){
    const int s0 = kt*64;
    const short* Vsc = Vs + (kt & 1)*(128*64);
    const bool alive = (s0 <= qr0 + 31);       // wave-uniform

    __syncthreads();   // A: implicit vmcnt(0) drain -> staged K/V visible

    f32x4 sacc[2][4];
    if (alive){
      #pragma unroll
      for (int rt = 0; rt < 2; ++rt)
        #pragma unroll
        for (int ct = 0; ct < 4; ++ct)
          sacc[rt][ct] = (f32x4){0.f, 0.f, 0.f, 0.f};
      // S = Q K^T (swizzled K reads)
      __builtin_amdgcn_s_setprio(1);
      #pragma unroll
      for (int kc = 0; kc < 4; ++kc){
        #pragma unroll
        for (int ct = 0; ct < 4; ++ct){
          int row = ct*16 + c16;
          bf16x8 bfr = *(const bf16x8*)(Ks + row*128 + (((g + 4*kc) ^ (row & 7)) << 3));
          sacc[0][ct] = __builtin_amdgcn_mfma_f32_16x16x32_bf16(qa[0][kc], bfr, sacc[0][ct], 0, 0, 0);
          sacc[1][ct] = __builtin_amdgcn_mfma_f32_16x16x32_bf16(qa[1][kc], bfr, sacc[1][ct], 0, 0, 0);
        }
      }
      __builtin_amdgcn_s_setprio(0);
    }

    __syncthreads();   // B: all K reads done block-wide

    // issue next-tile stages NOW: they fly under softmax + P + PV,
    // drained only at the next iteration's barrier A
    if (kt + 1 < nsteps){
      stage_k_tile(kb, s0 + 64, Ks, wave, g, c16);
      stage_v_tile(vb, s0 + 64, Vs + ((kt+1) & 1)*(128*64), wave, lane);
    }

    if (alive){
      // scale + causal mask (C layout: row = g*4+r, col = c16)
      const float scale = 0.08838834764831845f;
      #pragma unroll
      for (int rt = 0; rt < 2; ++rt){
        int rowb = qr0 + rt*16 + g*4;
        #pragma unroll
        for (int ct = 0; ct < 4; ++ct){
          int scol = s0 + ct*16 + c16;
          #pragma unroll
          for (int r = 0; r < 4; ++r){
            float v = sacc[rt][ct][r] * scale;
            sacc[rt][ct][r] = (scol <= rowb + r) ? v : -1e30f;
          }
        }
      }

      // online softmax update (row state replicated across 16-lane group)
      #pragma unroll
      for (int rt = 0; rt < 2; ++rt){
        #pragma unroll
        for (int r = 0; r < 4; ++r){
          float mx = fmaxf(fmaxf(sacc[rt][0][r], sacc[rt][1][r]),
                           fmaxf(sacc[rt][2][r], sacc[rt][3][r]));
          #pragma unroll
          for (int off = 1; off < 16; off <<= 1)
            mx = fmaxf(mx, __shfl_xor(mx, off));
          float mn = fmaxf(m_st[rt][r], mx);
          float al = __expf(m_st[rt][r] - mn);
          m_st[rt][r] = mn;
          float sum = 0.f;
          #pragma unroll
          for (int ct = 0; ct < 4; ++ct){
            float pv = __expf(sacc[rt][ct][r] - mn);
            sacc[rt][ct][r] = pv;
            sum += pv;
          }
          #pragma unroll
          for (int off = 1; off < 16; off <<= 1)
            sum += __shfl_xor(sum, off);
          l_st[rt][r] = l_st[rt][r]*al + sum;
          #pragma unroll
          for (int dt = 0; dt < 8; ++dt)
            oacc[rt][dt][r] *= al;
        }
      }

      // P -> per-wave LDS strip (swizzled scatter)
      #pragma unroll
      for (int rt = 0; rt < 2; ++rt)
        #pragma unroll
        for (int ct = 0; ct < 4; ++ct)
          #pragma unroll
          for (int r = 0; r < 4; ++r){
            int prow = rt*16 + g*4 + r;
            int pcol = ct*16 + c16;
            Pw[prow*64 + ((((pcol >> 3) ^ (prow & 7)) << 3) | (pcol & 7))] =
                (short)f2bf(sacc[rt][ct][r]);
          }

      // per-wave strip: lgkm drain + sched fence instead of __syncthreads
      asm volatile("s_waitcnt lgkmcnt(0)" ::: "memory");
      __builtin_amdgcn_sched_barrier(0);

      // O += P V  (swizzled P and V reads)
      __builtin_amdgcn_s_setprio(1);
      #pragma unroll
      for (int kc2 = 0; kc2 < 2; ++kc2){
        int pr0 = c16, pr1 = 16 + c16;
        bf16x8 pf0 = *(const bf16x8*)(Pw + pr0*64 + (((g + 4*kc2) ^ (pr0 & 7)) << 3));
        bf16x8 pf1 = *(const bf16x8*)(Pw + pr1*64 + (((g + 4*kc2) ^ (pr1 & 7)) << 3));
        #pragma unroll
        for (int dt = 0; dt < 8; ++dt){
          int vr = dt*16 + c16;
          bf16x8 vf = *(const bf16x8*)(Vsc + vr*64 + (((g + 4*kc2) ^ (vr & 7)) << 3));
          oacc[0][dt] = __builtin_amdgcn_mfma_f32_16x16x32_bf16(pf0, vf, oacc[0][dt], 0, 0, 0);
          oacc[1][dt] = __builtin_amdgcn_mfma_f32_16x16x32_bf16(pf1, vf, oacc[1][dt], 0, 0, 0);
        }
      }
      __builtin_amdgcn_s_setprio(0);
    }
  }

  // normalize + store (B,S,DIM)
  #pragma unroll
  for (int rt = 0; rt < 2; ++rt){
    float inv[4];
    #pragma unroll
    for (int r = 0; r < 4; ++r) inv[r] = 1.0f / l_st[rt][r];
    #pragma unroll
    for (int dt = 0; dt < 8; ++dt){
      #pragma unroll
      for (int r = 0; r < 4; ++r){
        int qrow = qr0 + rt*16 + g*4 + r;
        int col  = h*HD + dt*16 + c16;
        AO[(size_t)(b*SEQL + qrow)*DIMK + col] = f2bf(oacc[rt][dt][r] * inv[r]);
      }
    }
  }
}

extern "C" void kernel_launch(void* const* d_in, const int* in_sizes, int n_in,
                              void* d_out, int out_size, void* d_ws, size_t ws_size,
                              hipStream_t stream)
{
  const float* x  = (const float*)d_in[0];
  const float* wq = (const float*)d_in[1];
  const float* wk = (const float*)d_in[2];
  const float* wv = (const float*)d_in[3];
  const float* wo = (const float*)d_in[4];
  const float* fc = (const float*)d_in[5];
  const float* fs = (const float*)d_in[6];
  float* out = (float*)d_out;

  const size_t TEN  = (size_t)NROWS * DIMK;    // 16,777,216 elems
  const size_t TENB = TEN * sizeof(u16);       // 32 MiB
  const int N8 = (int)(TEN / 8);

  const dim3 GG(256), B512(512), B256(256);
  const dim3 FG(64, 16);                        // (bh, qtiles) — heavy-first inside

  if (ws_size >= 8 * TENB){
    u16* xb   = (u16*)d_ws;
    u16* wb   = xb   + TEN;
    u16* qb   = wb   + TEN;
    u16* kb   = qb   + TEN;
    u16* vraw = kb   + TEN;
    u16* vtb  = vraw + TEN;
    u16* qro  = vtb  + TEN;
    u16* kro  = qro  + TEN;
    cvt_kernel<<<dim3(8192), B256, 0, stream>>>(x,  xb, N8);
    cvt_kernel<<<dim3(8192), B256, 0, stream>>>(wq, wb, N8);
    gemm_bf16_kernel<<<GG, B512, 0, stream>>>(xb, wb, qb);
    cvt_kernel<<<dim3(8192), B256, 0, stream>>>(wk, wb, N8);
    gemm_bf16_kernel<<<GG, B512, 0, stream>>>(xb, wb, kb);
    cvt_kernel<<<dim3(8192), B256, 0, stream>>>(wv, wb, N8);
    gemm_bf16_kernel<<<GG, B512, 0, stream>>>(xb, wb, vraw);
    transpose_kernel<<<dim3(32, 2, 64), B256, 0, stream>>>(vraw, vtb);
    rope_kernel<<<dim3(16384), B256, 0, stream>>>(qb, kb, qro, kro, fc, fs);
    flash_kernel<<<FG, B256, 0, stream>>>(qro, kro, vtb, vraw); // AO->vraw
    cvt_kernel<<<dim3(8192), B256, 0, stream>>>(wo, xb, N8);    // xb dead
    gemm_f32_kernel<<<GG, B512, 0, stream>>>(vraw, xb, out);
  } else if (ws_size >= 4 * TENB){
    u16* xb  = (u16*)d_out;
    u16* wb  = xb + TEN;
    u16* qb  = (u16*)d_ws;
    u16* kb  = qb + TEN;
    u16* vtb = kb + TEN;
    u16* s3  = vtb + TEN;                       // Vraw, then roped-Q
    cvt_kernel<<<dim3(8192), B256, 0, stream>>>(x,  xb, N8);
    cvt_kernel<<<dim3(8192), B256, 0, stream>>>(wq, wb, N8);
    gemm_bf16_kernel<<<GG, B512, 0, stream>>>(xb, wb, qb);
    cvt_kernel<<<dim3(8192), B256, 0, stream>>>(wk, wb, N8);
    gemm_bf16_kernel<<<GG, B512, 0, stream>>>(xb, wb, kb);
    cvt_kernel<<<dim3(8192), B256, 0, stream>>>(wv, wb, N8);
    gemm_bf16_kernel<<<GG, B512, 0, stream>>>(xb, wb, s3);                 // Vraw
    transpose_kernel<<<dim3(32, 2, 64), B256, 0, stream>>>(s3, vtb);
    rope_kernel<<<dim3(16384), B256, 0, stream>>>(qb, kb, s3, xb, fc, fs); // qro=s3, kro=xb
    flash_kernel<<<FG, B256, 0, stream>>>(s3, xb, vtb, qb);                // AO->qb
    cvt_kernel<<<dim3(8192), B256, 0, stream>>>(wo, kb, N8);               // kb dead
    gemm_f32_kernel<<<GG, B512, 0, stream>>>(qb, kb, out);
  }
}

// Round 3
// 1012.806 us; speedup vs baseline: 1.4474x; 1.0243x over previous
//
#include <hip/hip_runtime.h>
#include <stdint.h>

#define DIMK 4096
#define HD 128
#define NH 32
#define SEQL 2048
#define BSZN 2
#define NROWS (BSZN*SEQL)   // 4096

typedef __bf16 bf16x8 __attribute__((ext_vector_type(8)));
typedef float f32x4 __attribute__((ext_vector_type(4)));
typedef unsigned short u16;
typedef unsigned int u32;

__device__ __forceinline__ float bf2f(u16 h){
  u32 u = ((u32)h) << 16; float f;
  __builtin_memcpy(&f, &u, 4); return f;
}
// round-to-nearest-even f32 -> bf16
__device__ __forceinline__ u16 f2bf(float f){
  u32 u; __builtin_memcpy(&u, &f, 4);
  return (u16)((u + 0x7fffu + ((u >> 16) & 1u)) >> 16);
}

// async global->LDS, 16B/lane; LDS dest is WAVE-UNIFORM base + lane*16B
__device__ __forceinline__ void gld_lds16(const void* g, void* l){
  __builtin_amdgcn_global_load_lds(
      (__attribute__((address_space(1))) void*)(uintptr_t)g,
      (__attribute__((address_space(3))) void*)(uintptr_t)l, 16, 0, 0);
}

// ---------------------------------------------------------------------------
// GEMM, 256x256 8-phase schedule (m201/T2+T3+T4+T5 port, plain HIP):
// C[m,n] = sum_k A[m,k]*B[n,k], A/B bf16 row-major 4096x4096.
// Round 3: m204 chunked XCD swizzle (each XCD = 2 consecutive tile-rows ->
// 4MB A-panel fits per-XCD L2) + lgkmcnt(8) hint at the 12-ds_read phases.
// ---------------------------------------------------------------------------
#define BARX __builtin_amdgcn_s_barrier()
#define LGKM0 asm volatile("s_waitcnt lgkmcnt(0)" ::: "memory")
#define LGKM8 asm volatile("s_waitcnt lgkmcnt(8)" ::: "memory")
#define VMC6  asm volatile("s_waitcnt vmcnt(6)"  ::: "memory")
#define SP1 __builtin_amdgcn_s_setprio(1)
#define SP0 __builtin_amdgcn_s_setprio(0)

#define LDA4(MB, Ab) do{ \
  _Pragma("unroll") for (int mi = 0; mi < 4; ++mi){ \
    const int m_ = (MB) + mi; \
    const short* _p = (Ab) + (m_>>2)*8192 + (m_&3)*2048 + rdA; \
    aF[mi][0] = *(const bf16x8*)(_p + ch0); \
    aF[mi][1] = *(const bf16x8*)(_p + ch1); } }while(0)

#define LDB2(NB, Bb) do{ \
  _Pragma("unroll") for (int ni = 0; ni < 2; ++ni){ \
    const int n_ = (NB) + ni; \
    const short* _p = (Bb) + (n_>>1)*8192 + (n_&1)*4096 + rdB; \
    bF[ni][0] = *(const bf16x8*)(_p + ch0); \
    bF[ni][1] = *(const bf16x8*)(_p + ch1); } }while(0)

#define MFMA16(MB, NB) do{ \
  _Pragma("unroll") for (int ks = 0; ks < 2; ++ks) \
  _Pragma("unroll") for (int mi = 0; mi < 4; ++mi) \
  _Pragma("unroll") for (int ni = 0; ni < 2; ++ni) \
    acc[(MB)+mi][(NB)+ni] = __builtin_amdgcn_mfma_f32_16x16x32_bf16( \
        aF[mi][ks], bF[ni][ks], acc[(MB)+mi][(NB)+ni], 0, 0, 0); }while(0)

#define STG_A(buf,h,kt) do{ \
    size_t _o = ((size_t)(h)<<19) + (size_t)(kt)*64; \
    short* _d = dA + (buf)*32768 + (h)*8192; \
    gld_lds16(sA[0]+_o, _d); gld_lds16(sA[1]+_o, _d+512); }while(0)

#define STG_B(buf,h,kt) do{ \
    size_t _o = ((size_t)(h)<<19) + (size_t)(kt)*64; \
    short* _d = dB + (buf)*32768 + (h)*8192; \
    gld_lds16(sB[0]+_o, _d); gld_lds16(sB[1]+_o, _d+512); }while(0)

template<int OUTF32>
__device__ __forceinline__ void gemm256_core(const u16* __restrict__ A,
                                             const u16* __restrict__ B,
                                             void* __restrict__ Cv,
                                             short* SMEM)
{
  const int tid  = threadIdx.x;
  const int wave = tid >> 6, lane = tid & 63;
  const int wm = wave >> 2, wn = wave & 3;
  const int g = lane >> 4, c16 = lane & 15;

  // m204 bijective chunked XCD swizzle: nwg=256, 8 XCDs, q=32.
  // XCD x owns wg in [x*32, x*32+32) = tile-rows {2x, 2x+1} x all 16 cols.
  const int bid = blockIdx.x;
  const int wg  = (bid & 7) * 32 + (bid >> 3);
  const int bx = wg >> 4, by = wg & 15;
  const int m0 = bx*256, n0 = by*256;

  // LDS read constants (shorts). chunk' = (ks*4+g) ^ (c16&7); ch1 = ch0 ^ 4chunks
  const int ch0 = ((g ^ (c16 & 7)) << 3);
  const int ch1 = ch0 ^ 32;
  const int rdA = wm*1024 + c16*64;
  const int rdB = wn*1024 + c16*64;

  // stage sources: wave w, load p covers rows j*8..j*8+7 (j=w*2+p) of the half;
  // global col pre-swizzled so linear LDS + swizzled read line up (rule #21)
  const int swzc = (((lane & 7) ^ ((lane >> 3) & 7)) << 3);
  const u16* sA[2]; const u16* sB[2];
  #pragma unroll
  for (int p = 0; p < 2; ++p){
    int rr = wave*16 + p*8 + (lane >> 3);
    sA[p] = A + (size_t)(m0 + rr)*DIMK + swzc;
    sB[p] = B + (size_t)(n0 + rr)*DIMK + swzc;
  }
  short* const dA = SMEM + wave*1024;
  short* const dB = SMEM + 16384 + wave*1024;

  const short* A0 = SMEM;
  const short* B0 = SMEM + 16384;
  const short* A1 = SMEM + 32768;
  const short* B1 = SMEM + 49152;

  f32x4 acc[8][4];
  #pragma unroll
  for (int m = 0; m < 8; ++m)
    #pragma unroll
    for (int n = 0; n < 4; ++n)
      acc[m][n] = (f32x4){0.f, 0.f, 0.f, 0.f};

  bf16x8 aF[4][2], bF[2][2];

  // prologue: buf0 <- tile 0 (all 4 halves), buf1 <- tile 1 (A0,B1,A1).
  // vmcnt(6) retires the 8 oldest loads = all of buf0.
  STG_A(0,0,0); STG_B(0,1,0); STG_A(0,1,0); STG_B(0,0,0);
  STG_A(1,0,1); STG_B(1,1,1); STG_A(1,1,1);
  VMC6; BARX;

  #pragma unroll 1
  for (int i = 0; i < 32; ++i){
    const int t1 = (2*i+1) & 63, t2 = (2*i+2) & 63, t3 = (2*i+3) & 63;
    // ---- p0: tile 2i, Q(m-lo, n-lo)
    LDA4(0, A0); LDB2(0, B0);
    STG_B(1, 0, t1);
    LGKM8;
    BARX; LGKM0;
    SP1; MFMA16(0, 0); SP0;
    BARX;
    // ---- p1: Q(m-lo, n-hi)
    LDB2(2, B0);
    STG_A(0, 0, t2);
    BARX; LGKM0;
    SP1; MFMA16(0, 2); SP0;
    BARX;
    // ---- p2: Q(m-hi, n-hi)
    LDA4(4, A0);
    STG_B(0, 1, t2);
    BARX; LGKM0;
    SP1; MFMA16(4, 2); SP0;
    BARX;
    // ---- p3: Q(m-hi, n-lo)  (B-lo re-read)
    LDB2(0, B0);
    STG_A(0, 1, t2);
    VMC6;
    BARX; LGKM0;
    SP1; MFMA16(4, 0); SP0;
    BARX;
    // ---- p4: tile 2i+1, Q(m-lo, n-lo)
    LDA4(0, A1); LDB2(0, B1);
    STG_B(0, 0, t2);
    LGKM8;
    BARX; LGKM0;
    SP1; MFMA16(0, 0); SP0;
    BARX;
    // ---- p5: Q(m-lo, n-hi)
    LDB2(2, B1);
    STG_A(1, 0, t3);
    BARX; LGKM0;
    SP1; MFMA16(0, 2); SP0;
    BARX;
    // ---- p6: Q(m-hi, n-hi)
    LDA4(4, A1);
    STG_B(1, 1, t3);
    BARX; LGKM0;
    SP1; MFMA16(4, 2); SP0;
    BARX;
    // ---- p7: Q(m-hi, n-lo)
    LDB2(0, B1);
    STG_A(1, 1, t3);
    VMC6;
    BARX; LGKM0;
    SP1; MFMA16(4, 0); SP0;
    BARX;
  }

  // epilogue: frag (m,n) -> rows m0+(2m+wm)*16+g*4+r, col n0+(4n+wn)*16+c16
  if constexpr (OUTF32 == 0){
    u16* C = (u16*)Cv;
    #pragma unroll
    for (int m = 0; m < 8; ++m){
      int row0 = m0 + (m*2 + wm)*16 + g*4;
      #pragma unroll
      for (int n = 0; n < 4; ++n){
        int col = n0 + (n*4 + wn)*16 + c16;
        #pragma unroll
        for (int r = 0; r < 4; ++r)
          C[(size_t)(row0 + r)*DIMK + col] = f2bf(acc[m][n][r]);
      }
    }
  } else {
    float* C = (float*)Cv;
    #pragma unroll
    for (int m = 0; m < 8; ++m){
      int row0 = m0 + (m*2 + wm)*16 + g*4;
      #pragma unroll
      for (int n = 0; n < 4; ++n){
        int col = n0 + (n*4 + wn)*16 + c16;
        #pragma unroll
        for (int r = 0; r < 4; ++r)
          C[(size_t)(row0 + r)*DIMK + col] = acc[m][n][r];
      }
    }
  }
}

__global__ __launch_bounds__(512, 2) void gemm_bf16_kernel(const u16* __restrict__ A,
    const u16* __restrict__ B, u16* __restrict__ C)
{
  __shared__ __align__(16) short SMEM[65536];   // 128 KiB
  gemm256_core<0>(A, B, C, SMEM);
}

__global__ __launch_bounds__(512, 2) void gemm_f32_kernel(const u16* __restrict__ A,
    const u16* __restrict__ B, float* __restrict__ C)
{
  __shared__ __align__(16) short SMEM[65536];
  gemm256_core<1>(A, B, C, SMEM);
}

// f32 -> bf16 bulk convert (RNE), 8 elems/thread
__global__ __launch_bounds__(256) void cvt_kernel(const float* __restrict__ src,
                                                  u16* __restrict__ dst, int n8)
{
  int t = blockIdx.x*256 + threadIdx.x;
  if (t >= n8) return;
  const f32x4* s = (const f32x4*)src + (size_t)t*2;
  f32x4 a = s[0], b = s[1];
  ushort4 lo, hi;
  lo.x = f2bf(a[0]); lo.y = f2bf(a[1]); lo.z = f2bf(a[2]); lo.w = f2bf(a[3]);
  hi.x = f2bf(b[0]); hi.y = f2bf(b[1]); hi.z = f2bf(b[2]); hi.w = f2bf(b[3]);
  ushort4* d = (ushort4*)dst + (size_t)t*2;
  d[0] = lo; d[1] = hi;
}

// ---------------------------------------------------------------------------
// V (B,S,DIM row-major) -> V^T ([b][h][d][s]); 64x64 LDS tile per block
// ---------------------------------------------------------------------------
__global__ __launch_bounds__(256) void transpose_kernel(const u16* __restrict__ v,
                                                        u16* __restrict__ vt)
{
  __shared__ u16 tile[64][72];
  const int t  = threadIdx.x;
  const int s0 = blockIdx.x * 64;
  const int d0 = blockIdx.y * 64;
  const int bh = blockIdx.z;
  const int b = bh >> 5, h = bh & 31;

  #pragma unroll
  for (int i = 0; i < 4; ++i){
    int row = i*16 + (t >> 4);
    int cc  = (t & 15) * 4;
    uint2 val = *(const uint2*)(v + (size_t)(b*SEQL + s0 + row)*DIMK + h*HD + d0 + cc);
    const u16* p4 = (const u16*)&val;
    #pragma unroll
    for (int j = 0; j < 4; ++j) tile[cc + j][row] = p4[j];
  }
  __syncthreads();
  #pragma unroll
  for (int i = 0; i < 4; ++i){
    int drow = i*16 + (t >> 4);
    int sc   = (t & 15) * 4;
    uint2 o; u16* po = (u16*)&o;
    #pragma unroll
    for (int j = 0; j < 4; ++j) po[j] = tile[drow][sc + j];
    *(uint2*)(vt + ((size_t)(b*NH + h)*HD + d0 + drow)*SEQL + s0 + sc) = o;
  }
}

// ---------------------------------------------------------------------------
// RoPE (interleaved pairs), OUT-OF-PLACE: qsrc->qdst, ksrc->kdst; freqs f32
// ---------------------------------------------------------------------------
__global__ __launch_bounds__(256) void rope_kernel(const u16* __restrict__ qsrc,
    const u16* __restrict__ ksrc, u16* __restrict__ qdst, u16* __restrict__ kdst,
    const float* __restrict__ fc, const float* __restrict__ fs)
{
  const size_t PER = (size_t)NROWS * DIMK / 8;
  size_t t = (size_t)blockIdx.x * 256 + threadIdx.x;
  const u16* src = qsrc; u16* dst = qdst;
  if (t >= PER){ src = ksrc; dst = kdst; t -= PER; }
  size_t e0 = t * 8;
  int row = (int)(e0 >> 12);
  int col = (int)(e0 & (DIMK-1));
  int s  = row & (SEQL-1);
  int i0 = (col & (HD-1)) >> 1;

  uint4 raw = *(const uint4*)(src + e0);
  u16* xs = (u16*)&raw;
  f32x4 c4 = *(const f32x4*)(fc + s*64 + i0);
  f32x4 s4 = *(const f32x4*)(fs + s*64 + i0);
  #pragma unroll
  for (int j = 0; j < 4; ++j){
    float e = bf2f(xs[2*j]), o = bf2f(xs[2*j+1]);
    float c = c4[j], sn = s4[j];
    xs[2*j]   = f2bf(e*c - o*sn);
    xs[2*j+1] = f2bf(e*sn + o*c);
  }
  *(uint4*)(dst + e0) = raw;
}

// ---------------------------------------------------------------------------
// Flash attention, causal. Round 3: Bc=128 (one softmax update + 3 barriers
// per 128 K-cols, was 2 updates + 4 barriers). K,V single-buffered swizzled
// [128][128] tiles (32 KB each); P strips 16 KB; LDS 80 KB -> 2 blocks/CU.
// Prefetch: K(t+1) issued after barrier B (flies under softmax+PV);
// V(t+1) issued after barrier C (drained at next A, covered by co-resident
// block). Wave-uniform triangle skips on diagonal steps.
// ---------------------------------------------------------------------------
__device__ __forceinline__ void stage_k128(const u16* kb, int s0, short* Ksd,
                                           int wave, int g, int c16){
  #pragma unroll
  for (int it = 0; it < 8; ++it){
    int rbase = it*16 + wave*4;       // wave-uniform
    int row = rbase + g;              // per-lane
    gld_lds16(kb + (size_t)(s0 + row)*DIMK + ((c16 ^ (row & 7)) << 3),
              Ksd + rbase*128);
  }
}
__device__ __forceinline__ void stage_v128(const u16* vb, int s0, short* Vd,
                                           int wave, int lane){
  const int sc = lane & 15, rg = lane >> 4;
  #pragma unroll
  for (int it = 0; it < 8; ++it){
    int rbase = it*16 + wave*4;       // wave-uniform
    int row = rbase + rg;             // per-lane (d index)
    gld_lds16(vb + (size_t)row*SEQL + s0 + ((sc ^ (row & 7)) << 3),
              Vd + rbase*128);
  }
}

__global__ __launch_bounds__(256) void flash_kernel(const u16* __restrict__ Q,
    const u16* __restrict__ K, const u16* __restrict__ Vt, u16* __restrict__ AO)
{
  __shared__ short Ks[128*128];      // [s][d] swizzled, single buffer (32 KB)
  __shared__ short Vs[128*128];      // [d][s] swizzled, single buffer (32 KB)
  __shared__ short Ps[4*32*64];      // per-wave P strips, swizzled (16 KB)

  const int bh = blockIdx.x;
  const int qt = 15 - (int)blockIdx.y;         // heavy diagonal first
  const int b = bh >> 5, h = bh & 31;
  const int tid = threadIdx.x;
  const int wave = tid >> 6, lane = tid & 63;
  const int g = lane >> 4, c16 = lane & 15;
  const int qr0 = qt*128 + wave*32;
  const int rmax = qr0 + 31;                   // wave's last (largest) q row

  const u16* kb = K  + (size_t)(b*SEQL)*DIMK + h*HD;
  const u16* vb = Vt + (size_t)(b*NH + h)*HD*SEQL;
  short* Pw = Ps + wave*(32*64);

  // prologue: get tile 0 flying before anything else
  stage_k128(kb, 0, Ks, wave, g, c16);
  stage_v128(vb, 0, Vs, wave, lane);

  bf16x8 qa[2][4];
  #pragma unroll
  for (int rt = 0; rt < 2; ++rt){
    const u16* qp = Q + (size_t)(b*SEQL + qr0 + rt*16 + c16)*DIMK + h*HD + g*8;
    #pragma unroll
    for (int kc = 0; kc < 4; ++kc)
      qa[rt][kc] = *(const bf16x8*)(qp + kc*32);
  }

  f32x4 oacc[2][8];
  #pragma unroll
  for (int rt = 0; rt < 2; ++rt)
    #pragma unroll
    for (int dt = 0; dt < 8; ++dt)
      oacc[rt][dt] = (f32x4){0.f, 0.f, 0.f, 0.f};
  float m_st[2][4], l_st[2][4];
  #pragma unroll
  for (int rt = 0; rt < 2; ++rt)
    #pragma unroll
    for (int r = 0; r < 4; ++r){ m_st[rt][r] = -1e30f; l_st[rt][r] = 0.f; }

  const int nsteps = qt + 1;
  for (int kt = 0; kt < nsteps; ++kt){
    const int s0 = kt*128;

    __syncthreads();   // A: implicit vmcnt(0) drain -> staged K/V visible

    // S = Q K^T over 128 cols (skip fully-masked ct tiles, wave-uniform)
    f32x4 sacc[2][8];
    #pragma unroll
    for (int rt = 0; rt < 2; ++rt)
      #pragma unroll
      for (int ct = 0; ct < 8; ++ct)
        sacc[rt][ct] = (f32x4){0.f, 0.f, 0.f, 0.f};
    __builtin_amdgcn_s_setprio(1);
    #pragma unroll
    for (int kc = 0; kc < 4; ++kc){
      #pragma unroll
      for (int ct = 0; ct < 8; ++ct){
        if (s0 + ct*16 > rmax) continue;       // wave-uniform dead tile
        int row = ct*16 + c16;
        bf16x8 bfr = *(const bf16x8*)(Ks + row*128 + (((g + 4*kc) ^ (row & 7)) << 3));
        sacc[0][ct] = __builtin_amdgcn_mfma_f32_16x16x32_bf16(qa[0][kc], bfr, sacc[0][ct], 0, 0, 0);
        sacc[1][ct] = __builtin_amdgcn_mfma_f32_16x16x32_bf16(qa[1][kc], bfr, sacc[1][ct], 0, 0, 0);
      }
    }
    __builtin_amdgcn_s_setprio(0);

    __syncthreads();   // B: all K reads done block-wide

    // prefetch next K now: flies under softmax + P + PV
    if (kt + 1 < nsteps)
      stage_k128(kb, s0 + 128, Ks, wave, g, c16);

    // scale + causal mask (C layout: row = g*4+r, col = c16).
    // mask ALL ct (incl. skipped tiles: their sacc=0 must become -1e30).
    const float scale = 0.08838834764831845f;
    #pragma unroll
    for (int rt = 0; rt < 2; ++rt){
      int rowb = qr0 + rt*16 + g*4;
      #pragma unroll
      for (int ct = 0; ct < 8; ++ct){
        int scol = s0 + ct*16 + c16;
        #pragma unroll
        for (int r = 0; r < 4; ++r){
          float v = sacc[rt][ct][r] * scale;
          sacc[rt][ct][r] = (scol <= rowb + r) ? v : -1e30f;
        }
      }
    }

    // online softmax update, ONCE per 128 cols
    #pragma unroll
    for (int rt = 0; rt < 2; ++rt){
      #pragma unroll
      for (int r = 0; r < 4; ++r){
        float mx = sacc[rt][0][r];
        #pragma unroll
        for (int ct = 1; ct < 8; ++ct) mx = fmaxf(mx, sacc[rt][ct][r]);
        #pragma unroll
        for (int off = 1; off < 16; off <<= 1)
          mx = fmaxf(mx, __shfl_xor(mx, off));
        float mn = fmaxf(m_st[rt][r], mx);
        float al = __expf(m_st[rt][r] - mn);
        m_st[rt][r] = mn;
        float sum = 0.f;
        #pragma unroll
        for (int ct = 0; ct < 8; ++ct){
          float pv = __expf(sacc[rt][ct][r] - mn);
          sacc[rt][ct][r] = pv;
          sum += pv;
        }
        #pragma unroll
        for (int off = 1; off < 16; off <<= 1)
          sum += __shfl_xor(sum, off);
        l_st[rt][r] = l_st[rt][r]*al + sum;
        #pragma unroll
        for (int dt = 0; dt < 8; ++dt)
          oacc[rt][dt][r] *= al;
      }
    }

    // O += P V in two 64-col chunks (strip reused; skip dead chunks)
    #pragma unroll
    for (int c = 0; c < 2; ++c){
      if (s0 + c*64 > rmax) continue;          // wave-uniform dead chunk

      // P chunk -> per-wave LDS strip (swizzled scatter)
      #pragma unroll
      for (int rt = 0; rt < 2; ++rt)
        #pragma unroll
        for (int ct = 0; ct < 4; ++ct)
          #pragma unroll
          for (int r = 0; r < 4; ++r){
            int prow = rt*16 + g*4 + r;
            int pcol = ct*16 + c16;
            Pw[prow*64 + ((((pcol >> 3) ^ (prow & 7)) << 3) | (pcol & 7))] =
                (short)f2bf(sacc[rt][c*4 + ct][r]);
          }

      // per-wave strip: lgkm drain + sched fence instead of __syncthreads
      asm volatile("s_waitcnt lgkmcnt(0)" ::: "memory");
      __builtin_amdgcn_sched_barrier(0);

      __builtin_amdgcn_s_setprio(1);
      #pragma unroll
      for (int kc2 = 0; kc2 < 2; ++kc2){
        int pr0 = c16, pr1 = 16 + c16;
        bf16x8 pf0 = *(const bf16x8*)(Pw + pr0*64 + (((g + 4*kc2) ^ (pr0 & 7)) << 3));
        bf16x8 pf1 = *(const bf16x8*)(Pw + pr1*64 + (((g + 4*kc2) ^ (pr1 & 7)) << 3));
        #pragma unroll
        for (int dt = 0; dt < 8; ++dt){
          int vr = dt*16 + c16;
          int chv = c*8 + kc2*4 + g;           // V s-chunk (0..15)
          bf16x8 vf = *(const bf16x8*)(Vs + vr*128 + ((chv ^ (vr & 7)) << 3));
          oacc[0][dt] = __builtin_amdgcn_mfma_f32_16x16x32_bf16(pf0, vf, oacc[0][dt], 0, 0, 0);
          oacc[1][dt] = __builtin_amdgcn_mfma_f32_16x16x32_bf16(pf1, vf, oacc[1][dt], 0, 0, 0);
        }
      }
      __builtin_amdgcn_s_setprio(0);
    }

    __syncthreads();   // C: all V reads done block-wide

    // prefetch next V (drained at next A; co-resident block covers latency)
    if (kt + 1 < nsteps)
      stage_v128(vb, s0 + 128, Vs, wave, lane);
  }

  // normalize + store (B,S,DIM)
  #pragma unroll
  for (int rt = 0; rt < 2; ++rt){
    float inv[4];
    #pragma unroll
    for (int r = 0; r < 4; ++r) inv[r] = 1.0f / l_st[rt][r];
    #pragma unroll
    for (int dt = 0; dt < 8; ++dt){
      #pragma unroll
      for (int r = 0; r < 4; ++r){
        int qrow = qr0 + rt*16 + g*4 + r;
        int col  = h*HD + dt*16 + c16;
        AO[(size_t)(b*SEQL + qrow)*DIMK + col] = f2bf(oacc[rt][dt][r] * inv[r]);
      }
    }
  }
}

extern "C" void kernel_launch(void* const* d_in, const int* in_sizes, int n_in,
                              void* d_out, int out_size, void* d_ws, size_t ws_size,
                              hipStream_t stream)
{
  const float* x  = (const float*)d_in[0];
  const float* wq = (const float*)d_in[1];
  const float* wk = (const float*)d_in[2];
  const float* wv = (const float*)d_in[3];
  const float* wo = (const float*)d_in[4];
  const float* fc = (const float*)d_in[5];
  const float* fs = (const float*)d_in[6];
  float* out = (float*)d_out;

  const size_t TEN  = (size_t)NROWS * DIMK;    // 16,777,216 elems
  const size_t TENB = TEN * sizeof(u16);       // 32 MiB
  const int N8 = (int)(TEN / 8);

  const dim3 GG(256), B512(512), B256(256);
  const dim3 FG(64, 16);                        // (bh, qtiles) — heavy-first inside

  if (ws_size >= 8 * TENB){
    u16* xb   = (u16*)d_ws;
    u16* wb   = xb   + TEN;
    u16* qb   = wb   + TEN;
    u16* kb   = qb   + TEN;
    u16* vraw = kb   + TEN;
    u16* vtb  = vraw + TEN;
    u16* qro  = vtb  + TEN;
    u16* kro  = qro  + TEN;
    cvt_kernel<<<dim3(8192), B256, 0, stream>>>(x,  xb, N8);
    cvt_kernel<<<dim3(8192), B256, 0, stream>>>(wq, wb, N8);
    gemm_bf16_kernel<<<GG, B512, 0, stream>>>(xb, wb, qb);
    cvt_kernel<<<dim3(8192), B256, 0, stream>>>(wk, wb, N8);
    gemm_bf16_kernel<<<GG, B512, 0, stream>>>(xb, wb, kb);
    cvt_kernel<<<dim3(8192), B256, 0, stream>>>(wv, wb, N8);
    gemm_bf16_kernel<<<GG, B512, 0, stream>>>(xb, wb, vraw);
    transpose_kernel<<<dim3(32, 2, 64), B256, 0, stream>>>(vraw, vtb);
    rope_kernel<<<dim3(16384), B256, 0, stream>>>(qb, kb, qro, kro, fc, fs);
    flash_kernel<<<FG, B256, 0, stream>>>(qro, kro, vtb, vraw); // AO->vraw
    cvt_kernel<<<dim3(8192), B256, 0, stream>>>(wo, xb, N8);    // xb dead
    gemm_f32_kernel<<<GG, B512, 0, stream>>>(vraw, xb, out);
  } else if (ws_size >= 4 * TENB){
    u16* xb  = (u16*)d_out;
    u16* wb  = xb + TEN;
    u16* qb  = (u16*)d_ws;
    u16* kb  = qb + TEN;
    u16* vtb = kb + TEN;
    u16* s3  = vtb + TEN;                       // Vraw, then roped-Q
    cvt_kernel<<<dim3(8192), B256, 0, stream>>>(x,  xb, N8);
    cvt_kernel<<<dim3(8192), B256, 0, stream>>>(wq, wb, N8);
    gemm_bf16_kernel<<<GG, B512, 0, stream>>>(xb, wb, qb);
    cvt_kernel<<<dim3(8192), B256, 0, stream>>>(wk, wb, N8);
    gemm_bf16_kernel<<<GG, B512, 0, stream>>>(xb, wb, kb);
    cvt_kernel<<<dim3(8192), B256, 0, stream>>>(wv, wb, N8);
    gemm_bf16_kernel<<<GG, B512, 0, stream>>>(xb, wb, s3);                 // Vraw
    transpose_kernel<<<dim3(32, 2, 64), B256, 0, stream>>>(s3, vtb);
    rope_kernel<<<dim3(16384), B256, 0, stream>>>(qb, kb, s3, xb, fc, fs); // qro=s3, kro=xb
    flash_kernel<<<FG, B256, 0, stream>>>(s3, xb, vtb, qb);                // AO->qb
    cvt_kernel<<<dim3(8192), B256, 0, stream>>>(wo, kb, N8);               // kb dead
    gemm_f32_kernel<<<GG, B512, 0, stream>>>(qb, kb, out);
  }
}